// Round 1
// baseline (209.436 us; speedup 1.0000x reference)
//
#include <hip/hip_runtime.h>
#include <math.h>

namespace {

constexpr int IN_DIM = 36;   // input features
constexpr int HID    = 8;    // f_in output
constexpr int AUD    = 32;   // final classes
constexpr int DI     = 24;   // d_inner
constexpr int NDB    = 9;    // dt_rank + 2*d_state

__device__ __forceinline__ float silu_f(float v) {
    return v / (1.0f + expf(-v));
}

__device__ __forceinline__ float softplus_f(float v) {
    // stable: max(v,0) + log1p(exp(-|v|))  (matches jax.nn.softplus)
    return fmaxf(v, 0.0f) + log1pf(expf(-fabsf(v)));
}

__global__ __launch_bounds__(256) void fused_audio_mamba(
    const float* __restrict__ x,          // [B,36]
    const float* __restrict__ f_in_w,     // [8,36]
    const float* __restrict__ f_in_b,     // [8]
    const float* __restrict__ f_out_w,    // [32,8]
    const float* __restrict__ f_out_b,    // [32]
    const float* __restrict__ in_proj_w,  // [48,8]
    const float* __restrict__ conv_w,     // [24,1,2]
    const float* __restrict__ conv_b,     // [24]
    const float* __restrict__ x_proj_w,   // [9,24]
    const float* __restrict__ dt_proj_w,  // [24,1]
    const float* __restrict__ dt_proj_b,  // [24]
    const float* __restrict__ Dp,         // [24]
    const float* __restrict__ out_proj_w, // [8,24]
    float* __restrict__ out,              // [B,32]
    int nrows)
{
    const int row = blockIdx.x * blockDim.x + threadIdx.x;
    if (row >= nrows) return;

    // ---- load x row (36 floats = 9 float4, row base 144B -> 16B aligned) ----
    float xr[IN_DIM];
    const float4* xp = reinterpret_cast<const float4*>(x + (size_t)row * IN_DIM);
    #pragma unroll
    for (int k = 0; k < IN_DIM / 4; ++k) {
        float4 v = xp[k];
        xr[4 * k + 0] = v.x; xr[4 * k + 1] = v.y;
        xr[4 * k + 2] = v.z; xr[4 * k + 3] = v.w;
    }

    // ---- u = x @ f_in_w^T + f_in_b : [8] ----
    float u[HID];
    #pragma unroll
    for (int j = 0; j < HID; ++j) {
        float acc = f_in_b[j];
        #pragma unroll
        for (int k = 0; k < IN_DIM; ++k)
            acc = fmaf(xr[k], f_in_w[j * IN_DIM + k], acc);
        u[j] = acc;
    }

    // ---- xz = u @ in_proj_w^T : xi = [:24], z = [24:48] ----
    float xi[DI], zz[DI];
    #pragma unroll
    for (int d = 0; d < DI; ++d) {
        float a = 0.0f, b = 0.0f;
        #pragma unroll
        for (int j = 0; j < HID; ++j) {
            a = fmaf(u[j], in_proj_w[d * HID + j], a);
            b = fmaf(u[j], in_proj_w[(d + DI) * HID + j], b);
        }
        xi[d] = a; zz[d] = b;
    }

    // ---- depthwise causal conv, L=1: only tap k=1 sees data; then silu ----
    #pragma unroll
    for (int d = 0; d < DI; ++d) {
        float v = fmaf(conv_w[2 * d + 1], xi[d], conv_b[d]);
        xi[d] = silu_f(v);
    }

    // ---- xdb = xi @ x_proj_w^T : [9] = [dt_raw(1), Bm(4), Cm(4)] ----
    float xdb[NDB];
    #pragma unroll
    for (int e = 0; e < NDB; ++e) {
        float acc = 0.0f;
        #pragma unroll
        for (int d = 0; d < DI; ++d)
            acc = fmaf(x_proj_w[e * DI + d], xi[d], acc);
        xdb[e] = acc;
    }
    const float dtr = xdb[0];
    // s = Bm . Cm  (scan with h0=0, L=1 collapses to this; dA/A_log drop out)
    const float s = xdb[1] * xdb[5] + xdb[2] * xdb[6]
                  + xdb[3] * xdb[7] + xdb[4] * xdb[8];

    // ---- y[d] = xi*(softplus(dtr*w+b)*s + Dp) * silu(z) ----
    float y[DI];
    #pragma unroll
    for (int d = 0; d < DI; ++d) {
        float dt = softplus_f(fmaf(dtr, dt_proj_w[d], dt_proj_b[d]));
        y[d] = xi[d] * fmaf(dt, s, Dp[d]) * silu_f(zz[d]);
    }

    // ---- o = y @ out_proj_w^T : [8] ----
    float o[HID];
    #pragma unroll
    for (int j = 0; j < HID; ++j) {
        float acc = 0.0f;
        #pragma unroll
        for (int d = 0; d < DI; ++d)
            acc = fmaf(out_proj_w[j * DI + d], y[d], acc);
        o[j] = acc;
    }

    // ---- logits = o @ f_out_w^T + f_out_b : [32], then softmax ----
    float lg[AUD];
    float mx = -INFINITY;
    #pragma unroll
    for (int c = 0; c < AUD; ++c) {
        float acc = f_out_b[c];
        #pragma unroll
        for (int j = 0; j < HID; ++j)
            acc = fmaf(f_out_w[c * HID + j], o[j], acc);
        lg[c] = acc;
        mx = fmaxf(mx, acc);
    }
    float ssum = 0.0f;
    #pragma unroll
    for (int c = 0; c < AUD; ++c) {
        lg[c] = expf(lg[c] - mx);
        ssum += lg[c];
    }
    const float inv = 1.0f / ssum;

    // ---- write 32 floats = 8 float4 (row base 128B aligned) ----
    float4* op = reinterpret_cast<float4*>(out + (size_t)row * AUD);
    #pragma unroll
    for (int k = 0; k < AUD / 4; ++k) {
        float4 v;
        v.x = lg[4 * k + 0] * inv;
        v.y = lg[4 * k + 1] * inv;
        v.z = lg[4 * k + 2] * inv;
        v.w = lg[4 * k + 3] * inv;
        op[k] = v;
    }
}

} // namespace

extern "C" void kernel_launch(void* const* d_in, const int* in_sizes, int n_in,
                              void* d_out, int out_size, void* d_ws, size_t ws_size,
                              hipStream_t stream) {
    const float* x          = (const float*)d_in[0];
    const float* f_in_w     = (const float*)d_in[1];
    const float* f_in_b     = (const float*)d_in[2];
    const float* f_out_w    = (const float*)d_in[3];
    const float* f_out_b    = (const float*)d_in[4];
    const float* in_proj_w  = (const float*)d_in[5];
    const float* conv_w     = (const float*)d_in[6];
    const float* conv_b     = (const float*)d_in[7];
    const float* x_proj_w   = (const float*)d_in[8];
    const float* dt_proj_w  = (const float*)d_in[9];
    const float* dt_proj_b  = (const float*)d_in[10];
    // d_in[11] = A_log: provably unused (L=1, h0=0 -> h = dBu; dA multiplies 0)
    const float* Dp         = (const float*)d_in[12];
    const float* out_proj_w = (const float*)d_in[13];
    float* out = (float*)d_out;

    const int nrows = in_sizes[0] / IN_DIM;  // 524288
    const int block = 256;
    const int grid  = (nrows + block - 1) / block;

    fused_audio_mamba<<<grid, block, 0, stream>>>(
        x, f_in_w, f_in_b, f_out_w, f_out_b, in_proj_w, conv_w, conv_b,
        x_proj_w, dt_proj_w, dt_proj_b, Dp, out_proj_w, out, nrows);
}

// Round 3
// 189.082 us; speedup vs baseline: 1.1076x; 1.1076x over previous
//
#include <hip/hip_runtime.h>
#include <math.h>

namespace {

constexpr int IN_DIM = 36;   // input features
constexpr int HID    = 8;    // f_in output
constexpr int AUD    = 32;   // final classes
constexpr int DI     = 24;   // d_inner
constexpr int NDB    = 9;    // dt_rank + 2*d_state

typedef float v2f __attribute__((ext_vector_type(2)));

__device__ __forceinline__ float hsum(v2f a) { return a.x + a.y; }

// fast silu: v / (1 + e^-v) with native v_exp_f32 + native divide (rcp+mul)
__device__ __forceinline__ float silu_f(float v) {
    return __fdividef(v, 1.0f + __expf(-v));
}

// fast stable softplus: max(v,0) + ln(1 + e^-|v|); log argument in (1,2] so
// native v_log_f32 relative accuracy is fine; v here is tiny (|v| < ~0.5).
__device__ __forceinline__ float softplus_f(float v) {
    return fmaxf(v, 0.0f) + __logf(1.0f + __expf(-fabsf(v)));
}

__global__ __launch_bounds__(256) void fused_audio_mamba(
    const float* __restrict__ x,          // [B,36]
    const float* __restrict__ f_in_w,     // [8,36]
    const float* __restrict__ f_in_b,     // [8]
    const float* __restrict__ f_out_w,    // [32,8]
    const float* __restrict__ f_out_b,    // [32]
    const float* __restrict__ in_proj_w,  // [48,8]
    const float* __restrict__ conv_w,     // [24,1,2]
    const float* __restrict__ conv_b,     // [24]
    const float* __restrict__ x_proj_w,   // [9,24]
    const float* __restrict__ dt_proj_w,  // [24,1]
    const float* __restrict__ dt_proj_b,  // [24]
    const float* __restrict__ Dp,         // [24]
    const float* __restrict__ out_proj_w, // [8,24]
    float* __restrict__ out,              // [B,32]
    int nrows)
{
    const int row = blockIdx.x * blockDim.x + threadIdx.x;
    if (row >= nrows) return;

    // packed-weight views (all rows have even float counts -> 8B aligned)
    const v2f* fw2 = reinterpret_cast<const v2f*>(f_in_w);     // [8][18]
    const v2f* ip2 = reinterpret_cast<const v2f*>(in_proj_w);  // [48][4]
    const v2f* xp2 = reinterpret_cast<const v2f*>(x_proj_w);   // [9][12]
    const v2f* op2 = reinterpret_cast<const v2f*>(out_proj_w); // [8][12]
    const v2f* fo2 = reinterpret_cast<const v2f*>(f_out_w);    // [32][4]

    // ---- load x row (36 floats = 9 float4, row base 144B -> 16B aligned) ----
    v2f xr2[IN_DIM / 2];
    const float4* xp = reinterpret_cast<const float4*>(x + (size_t)row * IN_DIM);
    #pragma unroll
    for (int k = 0; k < IN_DIM / 4; ++k) {
        float4 v = xp[k];
        xr2[2 * k + 0] = v2f{v.x, v.y};
        xr2[2 * k + 1] = v2f{v.z, v.w};
    }

    // ---- u = x @ f_in_w^T + f_in_b : [8]  (packed fp32 FMA) ----
    float u[HID];
    #pragma unroll
    for (int j = 0; j < HID; ++j) {
        v2f acc = v2f{f_in_b[j], 0.0f};
        #pragma unroll
        for (int k = 0; k < IN_DIM / 2; ++k)
            acc = __builtin_elementwise_fma(xr2[k], fw2[j * 18 + k], acc);
        u[j] = hsum(acc);
    }
    v2f u2[HID / 2];
    #pragma unroll
    for (int j = 0; j < HID / 2; ++j) u2[j] = v2f{u[2 * j], u[2 * j + 1]};

    // ---- xz = u @ in_proj_w^T : xi = [:24], z = [24:48] ----
    float xi[DI], zz[DI];
    #pragma unroll
    for (int d = 0; d < DI; ++d) {
        v2f a = v2f{0.0f, 0.0f}, b = v2f{0.0f, 0.0f};
        #pragma unroll
        for (int j = 0; j < HID / 2; ++j) {
            a = __builtin_elementwise_fma(u2[j], ip2[d * 4 + j], a);
            b = __builtin_elementwise_fma(u2[j], ip2[(d + DI) * 4 + j], b);
        }
        xi[d] = hsum(a); zz[d] = hsum(b);
    }

    // ---- depthwise causal conv, L=1: only tap k=1 sees data; then silu ----
    #pragma unroll
    for (int d = 0; d < DI; ++d) {
        float v = fmaf(conv_w[2 * d + 1], xi[d], conv_b[d]);
        xi[d] = silu_f(v);
    }
    v2f xi2[DI / 2];
    #pragma unroll
    for (int d = 0; d < DI / 2; ++d) xi2[d] = v2f{xi[2 * d], xi[2 * d + 1]};

    // ---- xdb = xi @ x_proj_w^T : [9] = [dt_raw(1), Bm(4), Cm(4)] ----
    float xdb[NDB];
    #pragma unroll
    for (int e = 0; e < NDB; ++e) {
        v2f acc = v2f{0.0f, 0.0f};
        #pragma unroll
        for (int d = 0; d < DI / 2; ++d)
            acc = __builtin_elementwise_fma(xp2[e * 12 + d], xi2[d], acc);
        xdb[e] = hsum(acc);
    }
    const float dtr = xdb[0];
    // s = Bm . Cm  (scan with h0=0, L=1 collapses to this; dA/A_log drop out)
    const float s = xdb[1] * xdb[5] + xdb[2] * xdb[6]
                  + xdb[3] * xdb[7] + xdb[4] * xdb[8];

    // ---- y[d] = xi*(softplus(dtr*w+b)*s + Dp) * silu(z) ----
    v2f y2[DI / 2];
    #pragma unroll
    for (int d = 0; d < DI; ++d) {
        float dt = softplus_f(fmaf(dtr, dt_proj_w[d], dt_proj_b[d]));
        float yv = xi[d] * fmaf(dt, s, Dp[d]) * silu_f(zz[d]);
        if (d & 1) y2[d / 2].y = yv; else y2[d / 2].x = yv;
    }

    // ---- o = y @ out_proj_w^T : [8] ----
    float o[HID];
    #pragma unroll
    for (int j = 0; j < HID; ++j) {
        v2f acc = v2f{0.0f, 0.0f};
        #pragma unroll
        for (int d = 0; d < DI / 2; ++d)
            acc = __builtin_elementwise_fma(op2[j * 12 + d], y2[d], acc);
        o[j] = hsum(acc);
    }
    v2f o2[HID / 2];
    #pragma unroll
    for (int j = 0; j < HID / 2; ++j) o2[j] = v2f{o[2 * j], o[2 * j + 1]};

    // ---- logits = o @ f_out_w^T + f_out_b : [32], then softmax ----
    float lg[AUD];
    float mx = -INFINITY;
    #pragma unroll
    for (int c = 0; c < AUD; ++c) {
        v2f acc = v2f{f_out_b[c], 0.0f};
        #pragma unroll
        for (int j = 0; j < HID / 2; ++j)
            acc = __builtin_elementwise_fma(fo2[c * 4 + j], o2[j], acc);
        lg[c] = hsum(acc);
        mx = fmaxf(mx, lg[c]);
    }
    float ssum = 0.0f;
    #pragma unroll
    for (int c = 0; c < AUD; ++c) {
        lg[c] = __expf(lg[c] - mx);
        ssum += lg[c];
    }
    const float inv = __fdividef(1.0f, ssum);

    // ---- write 32 floats = 8 float4 (row base 128B aligned) ----
    float4* op = reinterpret_cast<float4*>(out + (size_t)row * AUD);
    #pragma unroll
    for (int k = 0; k < AUD / 4; ++k) {
        float4 v;
        v.x = lg[4 * k + 0] * inv;
        v.y = lg[4 * k + 1] * inv;
        v.z = lg[4 * k + 2] * inv;
        v.w = lg[4 * k + 3] * inv;
        op[k] = v;
    }
}

} // namespace

extern "C" void kernel_launch(void* const* d_in, const int* in_sizes, int n_in,
                              void* d_out, int out_size, void* d_ws, size_t ws_size,
                              hipStream_t stream) {
    const float* x          = (const float*)d_in[0];
    const float* f_in_w     = (const float*)d_in[1];
    const float* f_in_b     = (const float*)d_in[2];
    const float* f_out_w    = (const float*)d_in[3];
    const float* f_out_b    = (const float*)d_in[4];
    const float* in_proj_w  = (const float*)d_in[5];
    const float* conv_w     = (const float*)d_in[6];
    const float* conv_b     = (const float*)d_in[7];
    const float* x_proj_w   = (const float*)d_in[8];
    const float* dt_proj_w  = (const float*)d_in[9];
    const float* dt_proj_b  = (const float*)d_in[10];
    // d_in[11] = A_log: provably unused (L=1, h0=0 -> h = dBu; dA multiplies 0)
    const float* Dp         = (const float*)d_in[12];
    const float* out_proj_w = (const float*)d_in[13];
    float* out = (float*)d_out;

    const int nrows = in_sizes[0] / IN_DIM;  // 524288
    const int block = 256;
    const int grid  = (nrows + block - 1) / block;

    fused_audio_mamba<<<grid, block, 0, stream>>>(
        x, f_in_w, f_in_b, f_out_w, f_out_b, in_proj_w, conv_w, conv_b,
        x_proj_w, dt_proj_w, dt_proj_b, Dp, out_proj_w, out, nrows);
}